// Round 14
// baseline (120.398 us; speedup 1.0000x reference)
//
#include <hip/hip_runtime.h>

// ---------------------------------------------------------------------------
// Self-attention: out = softmax((xWq)(xWk)^T / sqrt(64)) (xWv)
// B=4, N=4096, Din=128, Dout=64.  THREE kernels:
//   k1 qkv  : x@W (3-pass bf16 MFMA), W-conversion fused, trunc-pair hi/lo.
//   k2 attn : flash attention, 32-q waves. 128-reg-tier structure (round
//             13): two 32-key m-halves SEQUENTIAL (one f32x16 s, 8-reg pp),
//             K hi/lo LDS-staged (2x16KB dbuf, global_load_lds), V direct
//             from L2-hot global, launch_bounds(256,4), VGPR 64 / LDS 33KB
//             measured. THIS ROUND: NSEG=16, ITERS=4, grid 2048 = 8
//             blocks/CU QUEUED over ~4 resident — refill absorbs the
//             skip-variance tail that left round 13 at 29% occupancy
//             (grid 1024 = exact-fill, no refill, early finishers idled
//             CUs). Revert target if total >=118: round-11 config.
//   k3 merge: combine 16 segment partials (bf16 O partials).
// LESSON (round 7): no __threadfence+atomic merge fusion (device-scope
// fences = per-XCD L2 writebacks; trashed L2: 48->349us).
// LESSON (rounds 1-4): FETCH_SIZE is the spill tell.
// ---------------------------------------------------------------------------

typedef __attribute__((ext_vector_type(8))) short bf16x8;
typedef __attribute__((ext_vector_type(16))) float f32x16;
typedef __attribute__((ext_vector_type(4))) unsigned u32x4;
typedef unsigned short us;

__device__ __forceinline__ us f2bf(float f) {               // RTNE fp32->bf16
  unsigned u = __builtin_bit_cast(unsigned, f);
  u += 0x7FFFu + ((u >> 16) & 1u);
  return (us)(u >> 16);
}
__device__ __forceinline__ float bf2f(us h) {
  unsigned u = ((unsigned)h) << 16;
  return __builtin_bit_cast(float, u);
}
__device__ __forceinline__ float hi_part(float v) {         // trunc-bf16 as f32
  return __builtin_bit_cast(float,
         __builtin_bit_cast(unsigned, v) & 0xFFFF0000u);
}
__device__ __forceinline__ f32x16 mfma(bf16x8 a, bf16x8 b, f32x16 c) {
  return __builtin_amdgcn_mfma_f32_32x32x16_bf16(a, b, c, 0, 0, 0);
}
// truncating pack: low16 = bf16_trunc(a), high16 = bf16_trunc(b). ONE v_perm.
__device__ __forceinline__ unsigned pk2t(float a, float b) {
  return __builtin_amdgcn_perm(__builtin_bit_cast(unsigned, b),
                               __builtin_bit_cast(unsigned, a), 0x07060302u);
}
// async global->LDS DMA, 16B per lane. LDS dest is wave-uniform base
// (HW adds lane*16); global src is per-lane. Counts against vmcnt.
__device__ __forceinline__ void dma16(const us* g, us* l) {
  __builtin_amdgcn_global_load_lds(
      (const __attribute__((address_space(1))) unsigned*)g,
      (__attribute__((address_space(3))) unsigned*)l, 16, 0, 0);
}
#define EXP2(x) __builtin_amdgcn_exp2f(x)

#define NSEG 16
#define ITERS 4

// ---------------------------------------------------------------------------
// Kernel 1: QKV projection. 512 blocks x 384 thr (6 waves). Block = 32 rows
// x 192 cols. W conversion fused: wave wid needs B-frag elements
//   w[(wid>>1)*8192 + (ks*16+h*8+j)*64 + (wid&1)*32 + l31]
// scaled by 0.125*log2e when wid<2 (Q plane). hi/lo split via trunc-pair
// pk2t. K stored in A-frag tile order (64-key tile = 8KB contiguous,
// DMA-able by attn). UNCHANGED from round 13.
// ---------------------------------------------------------------------------
__global__ __launch_bounds__(384, 1) void qkv_kernel(
    const float* __restrict__ x, const float* __restrict__ w,
    us* __restrict__ Qhi, us* __restrict__ Qlo,
    us* __restrict__ Kbh, us* __restrict__ Kbl, us* __restrict__ Vb)
{
  __shared__ unsigned ttile[32 * 193];       // 24,704 B
  const int t = threadIdx.x;
  const int rb = blockIdx.x;                 // 0..511 (32 rows each)
  const int wid = t >> 6, lane = t & 63;     // wid = col group g, 0..5
  const int l31 = lane & 31, h = lane >> 5;
  const int rbase = rb * 32;
  const float* xrow = x + (size_t)(rbase + l31) * 128;

  // fused W prep: per-wave B-frags, hi/lo planes (trunc-pair), Q-scale folded
  bf16x8 wbh[8], wbl[8];
  {
    const float sc = (wid < 2) ? 0.18033688011112042f : 1.0f;
    const float* wp = w + (wid >> 1) * 8192 + (wid & 1) * 32 + l31 + h * 512;
    #pragma unroll
    for (int ks = 0; ks < 8; ++ks) {
      u32x4 hv, lv;
      #pragma unroll
      for (int jp = 0; jp < 4; ++jp) {
        const float va = wp[(ks * 16 + 2 * jp) * 64] * sc;
        const float vb = wp[(ks * 16 + 2 * jp + 1) * 64] * sc;
        hv[jp] = pk2t(va, vb);
        lv[jp] = pk2t(va - hi_part(va), vb - hi_part(vb));
      }
      wbh[ks] = __builtin_bit_cast(bf16x8, hv);
      wbl[ks] = __builtin_bit_cast(bf16x8, lv);
    }
  }

  f32x16 acc = {};
  #pragma unroll
  for (int ks = 0; ks < 8; ++ks) {           // K = 128 = 8 * 16
    const int d0 = ks * 16 + h * 8;
    const float4 xa = *(const float4*)(xrow + d0);
    const float4 xb = *(const float4*)(xrow + d0 + 4);
    const float xv[8] = {xa.x, xa.y, xa.z, xa.w, xb.x, xb.y, xb.z, xb.w};
    u32x4 ahv, alv;
    #pragma unroll
    for (int jp = 0; jp < 4; ++jp) {
      const float va = xv[2 * jp], vb = xv[2 * jp + 1];
      ahv[jp] = pk2t(va, vb);
      alv[jp] = pk2t(va - hi_part(va), vb - hi_part(vb));
    }
    const bf16x8 ah = __builtin_bit_cast(bf16x8, ahv);
    const bf16x8 al = __builtin_bit_cast(bf16x8, alv);
    acc = mfma(ah, wbh[ks], acc);
    acc = mfma(al, wbh[ks], acc);
    acc = mfma(ah, wbl[ks], acc);
  }

  // pack hi|lo into transpose tile. C layout: row=(r&3)+8*(r>>2)+4h, col=l31
  // Q/K (wid<4): trunc-pair. V (wid>=4): RTNE hi only (lo dead).
  const bool isV = (wid >= 4);
  #pragma unroll
  for (int r = 0; r < 16; ++r) {
    const int rl = (r & 3) + 8 * (r >> 2) + 4 * h;
    const float v = acc[r];
    const unsigned e = isV ? (unsigned)f2bf(v)
                           : pk2t(v, v - hi_part(v));
    ttile[rl * 193 + wid * 32 + l31] = e;
  }
  __syncthreads();

  // coalesced store phase (local cols: 0..63 Q, 64..127 K, 128..191 V)
  if (t < 64) {              // Q: row = t>>1, 32 cols each
    const int row = t >> 1, cb = (t & 1) * 32;
    const int grow = rbase + row;
    unsigned hw[16], lw[16];
    #pragma unroll
    for (int j = 0; j < 16; ++j) {
      unsigned a = ttile[row * 193 + cb + 2 * j];
      unsigned bv = ttile[row * 193 + cb + 2 * j + 1];
      hw[j] = (a & 0xffffu) | (bv << 16);
      lw[j] = (a >> 16) | (bv & 0xffff0000u);
    }
    #pragma unroll
    for (int j = 0; j < 4; ++j) {
      uint4 hv = {hw[4 * j], hw[4 * j + 1], hw[4 * j + 2], hw[4 * j + 3]};
      uint4 lv = {lw[4 * j], lw[4 * j + 1], lw[4 * j + 2], lw[4 * j + 3]};
      *(uint4*)(Qhi + (size_t)grow * 64 + cb + 8 * j) = hv;
      *(uint4*)(Qlo + (size_t)grow * 64 + cb + 8 * j) = lv;
    }
  } else if (t < 192) {      // K -> Kbh/Kbl A-frag tile layout
    const int bb = rbase >> 12;
    const int kt = (rbase & 4095) >> 6;
    const int m = (rbase >> 5) & 1;
    const size_t kbb = (size_t)bb * 262144 + (size_t)kt * 4096 + m * 256;
    #pragma unroll
    for (int i2 = 0; i2 < 2; ++i2) {
      const int c = (t - 64) + 128 * i2;     // 0..255
      const int r = c & 31, hh = (c >> 5) & 1, ks = c >> 6;
      unsigned hw[4], lw[4];
      #pragma unroll
      for (int j = 0; j < 4; ++j) {
        unsigned a = ttile[r * 193 + 64 + 16 * ks + 8 * hh + 2 * j];
        unsigned bv = ttile[r * 193 + 64 + 16 * ks + 8 * hh + 2 * j + 1];
        hw[j] = (a & 0xffffu) | (bv << 16);
        lw[j] = (a >> 16) | (bv & 0xffff0000u);
      }
      const size_t off = kbb + (size_t)(ks * 4 + 2 * hh) * 256 + r * 8;
      uint4 hv = {hw[0], hw[1], hw[2], hw[3]};
      uint4 lv = {lw[0], lw[1], lw[2], lw[3]};
      *(uint4*)(Kbh + off) = hv;
      *(uint4*)(Kbl + off) = lv;
    }
  } else if (t < 320) {      // V -> Vb B-frag layout (hi plane only)
    const int bb = rbase >> 12;
    const int nb = rbase & 4095;
    #pragma unroll
    for (int i2 = 0; i2 < 2; ++i2) {
      const int c = (t - 192) + 128 * i2;    // 0..255
      const int e = c >> 2, nc = c & 3;      // e 0..63, n-chunk 0..3
      unsigned p[4];
      #pragma unroll
      for (int j = 0; j < 4; ++j) {
        unsigned a = ttile[(nc * 8 + 2 * j) * 193 + 128 + e];
        unsigned bv = ttile[(nc * 8 + 2 * j + 1) * 193 + 128 + e];
        p[j] = (a & 0xffffu) | (bv << 16);
      }
      uint4 pv = {p[0], p[1], p[2], p[3]};
      const int n0 = nb + nc * 8;
      const int kt = n0 >> 6, sub = n0 & 63;
      const int ks = sub >> 4, hh = (sub >> 3) & 1;
      const int dt = e >> 5, lv = e & 31;
      *(uint4*)(Vb + (size_t)bb * 262144 +
                ((((kt * 4 + ks) * 2 + hh) * 2 + dt) * 256 + lv * 8)) = pv;
    }
  }
}

// ---------------------------------------------------------------------------
// Kernel 2: flash attention partials. 2048 blocks x 256 thr (4 waves of
// 32 q; all 4 waves share ONE key segment of 256 keys = 4 x 64-key tiles).
// 128-reg-tier structure: per 64-key tile the two 32-key m-halves are
// processed sequentially; K hi/lo in LDS (2x16KB dbuf); V direct from
// global. launch_bounds(256,4). Grid 2048 = 8 blocks/CU queued over ~4
// resident -> refill hides skip-variance tail.
// ---------------------------------------------------------------------------
__global__ __launch_bounds__(256, 4) void attn_kernel(
    const us* __restrict__ Qhi, const us* __restrict__ Qlo,
    const us* __restrict__ Kbh, const us* __restrict__ Kbl,
    const us* __restrict__ Vb,
    us* __restrict__ Opart, float* __restrict__ Mpart,
    float* __restrict__ Lpart)
{
  __shared__ us stage[2][8192];      // 2 x 16KB: [Khi 4096 us][Klo 4096 us]
  __shared__ float alds[4][32];

  // XCD-aware map: XCD x serves batch x>>1; seg parity follows xc&1.
  const int bx = blockIdx.x;
  const int xc = bx & 7, b = xc >> 1;
  const int idx = ((bx >> 3) << 1) | (xc & 1);      // 0..511
  const int seg = idx & (NSEG - 1), qg = idx >> 4;  // seg 0..15, qg 0..31
  const int t = threadIdx.x;
  const int wid = t >> 6, lane = t & 63;
  const int l31 = lane & 31, h = lane >> 5;
  const int q0 = qg * 128 + wid * 32;               // wave's first q
  const int u = (b * 4096 + q0) >> 5;               // global 32q unit
  const size_t pb = (size_t)u * NSEG + seg;

  // persistent Q B-frags: n=l31, k=16ks+8h+j
  bf16x8 qh[4], ql[4];
  {
    const size_t rg = (size_t)(b * 4096 + q0 + l31) * 64;
    #pragma unroll
    for (int ks = 0; ks < 4; ++ks) {
      qh[ks] = *(const bf16x8*)(Qhi + rg + ks * 16 + h * 8);
      ql[ks] = *(const bf16x8*)(Qlo + rg + ks * 16 + h * 8);
    }
  }
  const size_t kbase = (size_t)b * 262144;    // Kb / Vb per-batch base

  // prologue: DMA K tile 0 into stage[0] (16 chunks of 1KB, 4 per wave)
  {
    const size_t kb0 = kbase + (size_t)(seg * ITERS) * 4096;
    #pragma unroll
    for (int i = 0; i < 4; ++i) {
      const int c = wid * 4 + i;               // 0..15, wave-uniform
      const us* src = (c < 8) ? Kbh + kb0 + c * 512
                              : Kbl + kb0 + (c - 8) * 512;
      dma16(src + lane * 8, &stage[0][c * 512]);
    }
  }
  __syncthreads();   // vmcnt(0) drain + barrier: tile 0 resident

  f32x16 o[2] = {};
  float mrun = -__builtin_inff();
  float lrun = 0.f;

  for (int it = 0; it < ITERS; ++it) {
    const int cur = it & 1;
    const us* sb = &stage[cur][0];
    const int KT = seg * ITERS + it;          // global 64-key tile id

    // issue next K tile's DMA into the other buffer
    if (it + 1 < ITERS) {
      const size_t kbn = kbase + (size_t)(KT + 1) * 4096;
      #pragma unroll
      for (int i = 0; i < 4; ++i) {
        const int c = wid * 4 + i;
        const us* src = (c < 8) ? Kbh + kbn + c * 512
                                : Kbl + kbn + (c - 8) * 512;
        dma16(src + lane * 8, &stage[cur ^ 1][c * 512]);
      }
    }

    // two 32-key m-halves, processed sequentially (small live set)
    #pragma unroll
    for (int m = 0; m < 2; ++m) {
      // S^T half = K_half · Q^T (3-pass hi/lo), K A-frags from LDS
      f32x16 s = {};
      __builtin_amdgcn_s_setprio(1);
      #pragma unroll
      for (int ks = 0; ks < 4; ++ks) {
        const int ko = (ks * 4 + 2 * h + m) * 256 + l31 * 8;
        const bf16x8 ah = *(const bf16x8*)(sb + ko);
        const bf16x8 al = *(const bf16x8*)(sb + 4096 + ko);
        s = mfma(ah, qh[ks], s);
        s = mfma(al, qh[ks], s);
        s = mfma(ah, ql[ks], s);
      }
      __builtin_amdgcn_s_setprio(0);

      // half-tile max: two fmax chains, then cross-half lane swap
      float va = fmaxf(s[0], s[1]);
      float vb2 = fmaxf(s[2], s[3]);
      #pragma unroll
      for (int r = 4; r < 16; r += 2) {
        va = fmaxf(va, s[r]);
        vb2 = fmaxf(vb2, s[r + 1]);
      }
      float vm = fmaxf(va, vb2);
      vm = fmaxf(vm, __shfl_xor(vm, 32));

      // near-one-hot skip (finer 32-key granularity)
      if (!__all(vm <= mrun - 24.f)) {
        const float mnew = (vm > mrun + 0.5f) ? vm : mrun;
        const float alpha = EXP2(mrun - mnew);  // 1.0 when mnew==mrun
        float sm0 = 0.f, sm1 = 0.f;
        unsigned pp[8];
        #pragma unroll
        for (int p = 0; p < 8; ++p) {
          const float p0 = EXP2(s[2 * p] - mnew);
          const float p1 = EXP2(s[2 * p + 1] - mnew);
          sm0 += p0;
          sm1 += p1;
          pp[p] = pk2t(p0, p1);                 // one v_perm per pair
        }
        float sum = sm0 + sm1;
        sum += __shfl_xor(sum, 32);
        lrun = lrun * alpha + sum;
        mrun = mnew;

        // rescale O (rare; alds broadcast to C-layout rows; per-wave LDS)
        if (__any(alpha != 1.f)) {
          if (!h) alds[wid][l31] = alpha;
          #pragma unroll
          for (int g = 0; g < 4; ++g) {
            const float4 af4 = *(const float4*)(&alds[wid][8 * g + 4 * h]);
            #pragma unroll
            for (int rr = 0; rr < 4; ++rr) {
              const int r = 4 * g + rr;
              const float a = (rr == 0) ? af4.x : (rr == 1) ? af4.y
                             : (rr == 2) ? af4.z : af4.w;
              o[0][r] *= a;
              o[1][r] *= a;
            }
          }
        }

        // PV: 2 ks per half; P A-frags via permlane32_swap; V direct from
        // L2-hot frag-ordered global (2x512B contiguous per load pair).
        __builtin_amdgcn_s_setprio(1);
        #pragma unroll
        for (int ks2 = 0; ks2 < 2; ++ks2) {
          const int ksg = 2 * m + ks2;
          const size_t vo = kbase +
              (size_t)(((KT * 4 + ksg) * 2 + h) * 2) * 256 + l31 * 8;
          const bf16x8 vf0 = *(const bf16x8*)(Vb + vo);
          const bf16x8 vf1 = *(const bf16x8*)(Vb + vo + 256);
          const int base = 4 * ks2;
          unsigned wx = pp[base + 0], wz = pp[base + 2];
          unsigned wy = pp[base + 1], ww = pp[base + 3];
          asm("v_permlane32_swap_b32 %0, %1" : "+v"(wx), "+v"(wz));
          asm("v_permlane32_swap_b32 %0, %1" : "+v"(wy), "+v"(ww));
          u32x4 wv;
          wv.x = wx;
          wv.y = wy;
          wv.z = wz;
          wv.w = ww;
          const bf16x8 af = __builtin_bit_cast(bf16x8, wv);
          o[0] = mfma(af, vf0, o[0]);
          o[1] = mfma(af, vf1, o[1]);
        }
        __builtin_amdgcn_s_setprio(0);
      }
    }

    // drain next-tile DMA (landed during compute) + protect buffer swap
    __syncthreads();
  }

  // epilogue: O -> bf16 Opart via LDS bounce aliasing the dead stage
  // buffers (per-wave 32x34 f32 region), two dt passes. No barriers.
  float* fw = ((float*)&stage[0][0]) + wid * (32 * 34);
  #pragma unroll
  for (int dt = 0; dt < 2; ++dt) {
    #pragma unroll
    for (int r = 0; r < 16; ++r) {
      const int qrow = (r & 3) + 8 * (r >> 2) + 4 * h;  // 0..31
      fw[qrow * 34 + l31] = o[dt][r];
    }
    #pragma unroll
    for (int jj = 0; jj < 2; ++jj) {
      const int chunk = lane + 64 * jj;           // 0..127
      const int rw = chunk >> 2, part = chunk & 3;
      const float* src = &fw[rw * 34 + part * 8];
      float2 a0 = *(const float2*)(src + 0);
      float2 a1 = *(const float2*)(src + 2);
      float2 a2 = *(const float2*)(src + 4);
      float2 a3 = *(const float2*)(src + 6);
      uint4 pkv;
      pkv.x = pk2t(a0.x, a0.y);
      pkv.y = pk2t(a1.x, a1.y);
      pkv.z = pk2t(a2.x, a2.y);
      pkv.w = pk2t(a3.x, a3.y);
      *(uint4*)(Opart + pb * 2048 + (size_t)rw * 64 + dt * 32 + part * 8) =
          pkv;
    }
  }
  if (!h) {
    Mpart[pb * 32 + l31] = mrun;
    Lpart[pb * 32 + l31] = lrun;
  }
}

// ---------------------------------------------------------------------------
// Kernel 3: merge 16 key-segment partials (bf16). 131072 thr, 8 d each.
// ---------------------------------------------------------------------------
__global__ __launch_bounds__(256, 1) void merge_kernel(
    const us* __restrict__ Opart, const float* __restrict__ Mpart,
    const float* __restrict__ Lpart, float* __restrict__ out)
{
  const int tg = blockIdx.x * 256 + threadIdx.x;
  const int q = tg >> 3, dc = (tg & 7) * 8;
  const int u = q >> 5, ql = q & 31;
  const int base = u * NSEG;
  float M = -__builtin_inff();
  #pragma unroll
  for (int s = 0; s < NSEG; ++s)
    M = fmaxf(M, Mpart[(size_t)(base + s) * 32 + ql]);
  float acc[8] = {};
  float den = 0.f;
  #pragma unroll
  for (int s = 0; s < NSEG; ++s) {
    const float wgt = EXP2(Mpart[(size_t)(base + s) * 32 + ql] - M);
    den += wgt * Lpart[(size_t)(base + s) * 32 + ql];
    const uint4 r = *(const uint4*)(Opart + (size_t)(base + s) * 2048 +
                                    ql * 64 + dc);
    const unsigned rw[4] = {r.x, r.y, r.z, r.w};
    #pragma unroll
    for (int j = 0; j < 4; ++j) {
      acc[2 * j]     += wgt * bf2f((us)(rw[j] & 0xffffu));
      acc[2 * j + 1] += wgt * bf2f((us)(rw[j] >> 16));
    }
  }
  const float inv = 1.f / den;
  float4 r0 = {acc[0] * inv, acc[1] * inv, acc[2] * inv, acc[3] * inv};
  float4 r1 = {acc[4] * inv, acc[5] * inv, acc[6] * inv, acc[7] * inv};
  *(float4*)(out + (size_t)q * 64 + dc) = r0;
  *(float4*)(out + (size_t)q * 64 + dc + 4) = r1;
}

// ---------------------------------------------------------------------------
extern "C" void kernel_launch(void* const* d_in, const int* in_sizes, int n_in,
                              void* d_out, int out_size, void* d_ws,
                              size_t ws_size, hipStream_t stream)
{
  const float* x = (const float*)d_in[0];
  const float* w = (const float*)d_in[1];
  float* out = (float*)d_out;
  char* ws = (char*)d_ws;

  const size_t T = 2097152;  // bytes per bf16 [4,4096,64] tensor
  us* Qhi = (us*)(ws + 0 * T);
  us* Qlo = (us*)(ws + 1 * T);
  us* Kbh = (us*)(ws + 2 * T);
  us* Kbl = (us*)(ws + 3 * T);
  us* Vb  = (us*)(ws + 4 * T);
  char* pbase = ws + 5 * T;
  us* Opart = (us*)pbase;                                    // 33,554,432 B
  float* Mpart = (float*)(pbase + 33554432);                 //  1,048,576 B
  float* Lpart = (float*)(pbase + 33554432 + 1048576);       //  1,048,576 B
  // total workspace use: ~44.1 MiB

  hipLaunchKernelGGL(qkv_kernel, dim3(512), dim3(384), 0, stream,
                     x, w, Qhi, Qlo, Kbh, Kbl, Vb);
  hipLaunchKernelGGL(attn_kernel, dim3(2048), dim3(256), 0, stream,
                     Qhi, Qlo, Kbh, Kbl, Vb, Opart, Mpart, Lpart);
  hipLaunchKernelGGL(merge_kernel, dim3(512), dim3(256), 0, stream,
                     Opart, Mpart, Lpart, out);
}

// Round 15
// 116.239 us; speedup vs baseline: 1.0358x; 1.0358x over previous
//
#include <hip/hip_runtime.h>

// ---------------------------------------------------------------------------
// Self-attention: out = softmax((xWq)(xWk)^T / sqrt(64)) (xWv)
// B=4, N=4096, Din=128, Dout=64.  THREE kernels. FINAL CONFIG = round 11
// (best measured total 116.86us; rounds 12-14's 128-reg-tier restructure
// gave the best attn time, 47.5us, but its NSEG=8/16 partial-traffic and
// skip-maturity costs made totals 118.2/120.4 — net worse).
//   k1 qkv  : x@W (3-pass bf16 MFMA), W-conversion fused, trunc-pair hi/lo
//             (hi plane truncated for pair-consumed values; lo absorbs
//             hi's rounding; V keeps RTNE hi, lo plane dead).
//   k2 attn : flash attention, 32-q waves, NSEG=4 (ITERS=16, grid 512 =
//             2 blocks/CU, exact fill at the measured 2-resident
//             occupancy). K/V LDS-staged 24KB/tile via global_load_lds
//             double-buffer; permlane32_swap PV exchange;
//             launch_bounds(256,3) — live set ~150 unified regs (caps
//             85/128 spilled 1.2GB/190MB; cap ~170 = zero spill).
//   k3 merge: combine 4 segment partials (bf16 O partials).
// LESSON (round 7): no __threadfence+atomic merge fusion — device-scope
// fences are per-XCD L2 writeback/invalidates; 8192 of them trashed the
// L2-hot K/V set (FETCH 3.4x, attn 48->349us).
// LESSON (rounds 1-4): FETCH_SIZE is the spill tell.
// Session ledger: total ~= attn + ~67us (launch/harness floor + qkv ~10us
// + merge ~5us); qkv VALU-diet and kernel-count probes both ~1-2us.
// ---------------------------------------------------------------------------

typedef __attribute__((ext_vector_type(8))) short bf16x8;
typedef __attribute__((ext_vector_type(16))) float f32x16;
typedef __attribute__((ext_vector_type(4))) unsigned u32x4;
typedef unsigned short us;

__device__ __forceinline__ us f2bf(float f) {               // RTNE fp32->bf16
  unsigned u = __builtin_bit_cast(unsigned, f);
  u += 0x7FFFu + ((u >> 16) & 1u);
  return (us)(u >> 16);
}
__device__ __forceinline__ float bf2f(us h) {
  unsigned u = ((unsigned)h) << 16;
  return __builtin_bit_cast(float, u);
}
__device__ __forceinline__ float hi_part(float v) {         // trunc-bf16 as f32
  return __builtin_bit_cast(float,
         __builtin_bit_cast(unsigned, v) & 0xFFFF0000u);
}
__device__ __forceinline__ f32x16 mfma(bf16x8 a, bf16x8 b, f32x16 c) {
  return __builtin_amdgcn_mfma_f32_32x32x16_bf16(a, b, c, 0, 0, 0);
}
// truncating pack: low16 = bf16_trunc(a), high16 = bf16_trunc(b). ONE v_perm.
__device__ __forceinline__ unsigned pk2t(float a, float b) {
  return __builtin_amdgcn_perm(__builtin_bit_cast(unsigned, b),
                               __builtin_bit_cast(unsigned, a), 0x07060302u);
}
// async global->LDS DMA, 16B per lane. LDS dest is wave-uniform base
// (HW adds lane*16); global src is per-lane. Counts against vmcnt.
__device__ __forceinline__ void dma16(const us* g, us* l) {
  __builtin_amdgcn_global_load_lds(
      (const __attribute__((address_space(1))) unsigned*)g,
      (__attribute__((address_space(3))) unsigned*)l, 16, 0, 0);
}
#define EXP2(x) __builtin_amdgcn_exp2f(x)

#define NSEG 4
#define ITERS 16

// ---------------------------------------------------------------------------
// Kernel 1: QKV projection. 512 blocks x 384 thr (6 waves). Block = 32 rows
// x 192 cols. W conversion fused: wave wid needs B-frag elements
//   w[(wid>>1)*8192 + (ks*16+h*8+j)*64 + (wid&1)*32 + l31]
// scaled by 0.125*log2e when wid<2 (Q plane). hi/lo split via trunc-pair
// pk2t. K stored in A-frag tile order (64-key tile = 8KB contiguous,
// DMA-able by attn).
// ---------------------------------------------------------------------------
__global__ __launch_bounds__(384, 1) void qkv_kernel(
    const float* __restrict__ x, const float* __restrict__ w,
    us* __restrict__ Qhi, us* __restrict__ Qlo,
    us* __restrict__ Kbh, us* __restrict__ Kbl, us* __restrict__ Vb)
{
  __shared__ unsigned ttile[32 * 193];       // 24,704 B
  const int t = threadIdx.x;
  const int rb = blockIdx.x;                 // 0..511 (32 rows each)
  const int wid = t >> 6, lane = t & 63;     // wid = col group g, 0..5
  const int l31 = lane & 31, h = lane >> 5;
  const int rbase = rb * 32;
  const float* xrow = x + (size_t)(rbase + l31) * 128;

  // fused W prep: per-wave B-frags, hi/lo planes (trunc-pair), Q-scale folded
  bf16x8 wbh[8], wbl[8];
  {
    const float sc = (wid < 2) ? 0.18033688011112042f : 1.0f;
    const float* wp = w + (wid >> 1) * 8192 + (wid & 1) * 32 + l31 + h * 512;
    #pragma unroll
    for (int ks = 0; ks < 8; ++ks) {
      u32x4 hv, lv;
      #pragma unroll
      for (int jp = 0; jp < 4; ++jp) {
        const float va = wp[(ks * 16 + 2 * jp) * 64] * sc;
        const float vb = wp[(ks * 16 + 2 * jp + 1) * 64] * sc;
        hv[jp] = pk2t(va, vb);
        lv[jp] = pk2t(va - hi_part(va), vb - hi_part(vb));
      }
      wbh[ks] = __builtin_bit_cast(bf16x8, hv);
      wbl[ks] = __builtin_bit_cast(bf16x8, lv);
    }
  }

  f32x16 acc = {};
  #pragma unroll
  for (int ks = 0; ks < 8; ++ks) {           // K = 128 = 8 * 16
    const int d0 = ks * 16 + h * 8;
    const float4 xa = *(const float4*)(xrow + d0);
    const float4 xb = *(const float4*)(xrow + d0 + 4);
    const float xv[8] = {xa.x, xa.y, xa.z, xa.w, xb.x, xb.y, xb.z, xb.w};
    u32x4 ahv, alv;
    #pragma unroll
    for (int jp = 0; jp < 4; ++jp) {
      const float va = xv[2 * jp], vb = xv[2 * jp + 1];
      ahv[jp] = pk2t(va, vb);
      alv[jp] = pk2t(va - hi_part(va), vb - hi_part(vb));
    }
    const bf16x8 ah = __builtin_bit_cast(bf16x8, ahv);
    const bf16x8 al = __builtin_bit_cast(bf16x8, alv);
    acc = mfma(ah, wbh[ks], acc);
    acc = mfma(al, wbh[ks], acc);
    acc = mfma(ah, wbl[ks], acc);
  }

  // pack hi|lo into transpose tile. C layout: row=(r&3)+8*(r>>2)+4h, col=l31
  // Q/K (wid<4): trunc-pair. V (wid>=4): RTNE hi only (lo dead).
  const bool isV = (wid >= 4);
  #pragma unroll
  for (int r = 0; r < 16; ++r) {
    const int rl = (r & 3) + 8 * (r >> 2) + 4 * h;
    const float v = acc[r];
    const unsigned e = isV ? (unsigned)f2bf(v)
                           : pk2t(v, v - hi_part(v));
    ttile[rl * 193 + wid * 32 + l31] = e;
  }
  __syncthreads();

  // coalesced store phase (local cols: 0..63 Q, 64..127 K, 128..191 V)
  if (t < 64) {              // Q: row = t>>1, 32 cols each
    const int row = t >> 1, cb = (t & 1) * 32;
    const int grow = rbase + row;
    unsigned hw[16], lw[16];
    #pragma unroll
    for (int j = 0; j < 16; ++j) {
      unsigned a = ttile[row * 193 + cb + 2 * j];
      unsigned bv = ttile[row * 193 + cb + 2 * j + 1];
      hw[j] = (a & 0xffffu) | (bv << 16);
      lw[j] = (a >> 16) | (bv & 0xffff0000u);
    }
    #pragma unroll
    for (int j = 0; j < 4; ++j) {
      uint4 hv = {hw[4 * j], hw[4 * j + 1], hw[4 * j + 2], hw[4 * j + 3]};
      uint4 lv = {lw[4 * j], lw[4 * j + 1], lw[4 * j + 2], lw[4 * j + 3]};
      *(uint4*)(Qhi + (size_t)grow * 64 + cb + 8 * j) = hv;
      *(uint4*)(Qlo + (size_t)grow * 64 + cb + 8 * j) = lv;
    }
  } else if (t < 192) {      // K -> Kbh/Kbl A-frag tile layout
    const int bb = rbase >> 12;
    const int kt = (rbase & 4095) >> 6;
    const int m = (rbase >> 5) & 1;
    const size_t kbb = (size_t)bb * 262144 + (size_t)kt * 4096 + m * 256;
    #pragma unroll
    for (int i2 = 0; i2 < 2; ++i2) {
      const int c = (t - 64) + 128 * i2;     // 0..255
      const int r = c & 31, hh = (c >> 5) & 1, ks = c >> 6;
      unsigned hw[4], lw[4];
      #pragma unroll
      for (int j = 0; j < 4; ++j) {
        unsigned a = ttile[r * 193 + 64 + 16 * ks + 8 * hh + 2 * j];
        unsigned bv = ttile[r * 193 + 64 + 16 * ks + 8 * hh + 2 * j + 1];
        hw[j] = (a & 0xffffu) | (bv << 16);
        lw[j] = (a >> 16) | (bv & 0xffff0000u);
      }
      const size_t off = kbb + (size_t)(ks * 4 + 2 * hh) * 256 + r * 8;
      uint4 hv = {hw[0], hw[1], hw[2], hw[3]};
      uint4 lv = {lw[0], lw[1], lw[2], lw[3]};
      *(uint4*)(Kbh + off) = hv;
      *(uint4*)(Kbl + off) = lv;
    }
  } else if (t < 320) {      // V -> Vb B-frag layout (hi plane only)
    const int bb = rbase >> 12;
    const int nb = rbase & 4095;
    #pragma unroll
    for (int i2 = 0; i2 < 2; ++i2) {
      const int c = (t - 192) + 128 * i2;    // 0..255
      const int e = c >> 2, nc = c & 3;      // e 0..63, n-chunk 0..3
      unsigned p[4];
      #pragma unroll
      for (int j = 0; j < 4; ++j) {
        unsigned a = ttile[(nc * 8 + 2 * j) * 193 + 128 + e];
        unsigned bv = ttile[(nc * 8 + 2 * j + 1) * 193 + 128 + e];
        p[j] = (a & 0xffffu) | (bv << 16);
      }
      uint4 pv = {p[0], p[1], p[2], p[3]};
      const int n0 = nb + nc * 8;
      const int kt = n0 >> 6, sub = n0 & 63;
      const int ks = sub >> 4, hh = (sub >> 3) & 1;
      const int dt = e >> 5, lv = e & 31;
      *(uint4*)(Vb + (size_t)bb * 262144 +
                ((((kt * 4 + ks) * 2 + hh) * 2 + dt) * 256 + lv * 8)) = pv;
    }
  }
}

// ---------------------------------------------------------------------------
// Kernel 2: flash attention partials. 512 blocks x 256 thr (4 waves of
// 32 q; all 4 waves share ONE key segment of 1024 keys = 16 x 64-key
// tiles). Per tile: 24KB staged in LDS (Khi 8K | Klo 8K | V 8K),
// double-buffered via global_load_lds; __syncthreads() at tile end drains
// (vmcnt 0) and protects the swap. PV A-frag exchange =
// v_permlane32_swap_b32. Grid 512 = 2 blocks/CU = one exactly-filled
// round at the measured 2-resident occupancy.
// ---------------------------------------------------------------------------
__global__ __launch_bounds__(256, 3) void attn_kernel(
    const us* __restrict__ Qhi, const us* __restrict__ Qlo,
    const us* __restrict__ Kbh, const us* __restrict__ Kbl,
    const us* __restrict__ Vb,
    us* __restrict__ Opart, float* __restrict__ Mpart,
    float* __restrict__ Lpart)
{
  __shared__ us stage[2][12288];     // 2 x 24KB: [Khi 4096][Klo 4096][V 4096] us
  __shared__ float alds[4][32];

  // XCD-aware map: XCD x serves batch x>>1; seg parity follows xc&1 so
  // each XCD's L2 holds half the segments of its batch.
  const int bx = blockIdx.x;
  const int xc = bx & 7, b = xc >> 1;
  const int idx = ((bx >> 3) << 1) | (xc & 1);      // 0..127
  const int seg = idx & (NSEG - 1);                 // 0..3
  const int qg = idx / NSEG;                        // 0..31
  const int t = threadIdx.x;
  const int wid = t >> 6, lane = t & 63;
  const int l31 = lane & 31, h = lane >> 5;
  const int q0 = qg * 128 + wid * 32;               // wave's first q
  const int u = (b * 4096 + q0) >> 5;               // global 32q unit
  const size_t pb = (size_t)u * NSEG + seg;

  // persistent Q B-frags: n=l31, k=16ks+8h+j
  bf16x8 qh[4], ql[4];
  {
    const size_t rg = (size_t)(b * 4096 + q0 + l31) * 64;
    #pragma unroll
    for (int ks = 0; ks < 4; ++ks) {
      qh[ks] = *(const bf16x8*)(Qhi + rg + ks * 16 + h * 8);
      ql[ks] = *(const bf16x8*)(Qlo + rg + ks * 16 + h * 8);
    }
  }
  const size_t kbase = (size_t)b * 262144;    // Kb / Vb per-batch base

  // prologue: DMA tile 0 into stage[0]
  {
    const size_t kb0 = kbase + (size_t)(seg * ITERS) * 4096;
    #pragma unroll
    for (int i = 0; i < 6; ++i) {
      const int c = wid * 6 + i;               // 0..23, wave-uniform
      const us* src = (c < 8)  ? Kbh + kb0 + c * 512
                    : (c < 16) ? Kbl + kb0 + (c - 8) * 512
                               : Vb  + kb0 + (c - 16) * 512;
      dma16(src + lane * 8, &stage[0][c * 512]);
    }
  }
  __syncthreads();   // vmcnt(0) drain + barrier: tile 0 resident

  f32x16 o[2] = {};
  float mrun = -__builtin_inff();
  float lrun = 0.f;

  for (int it = 0; it < ITERS; ++it) {
    const int cur = it & 1;
    const us* sb = &stage[cur][0];

    // issue next tile's DMA into the other buffer (covered by this tile's
    // compute; drained by the __syncthreads at loop end)
    if (it + 1 < ITERS) {
      const size_t kbn = kbase + (size_t)(seg * ITERS + it + 1) * 4096;
      #pragma unroll
      for (int i = 0; i < 6; ++i) {
        const int c = wid * 6 + i;
        const us* src = (c < 8)  ? Kbh + kbn + c * 512
                      : (c < 16) ? Kbl + kbn + (c - 8) * 512
                                 : Vb  + kbn + (c - 16) * 512;
        dma16(src + lane * 8, &stage[cur ^ 1][c * 512]);
      }
    }

    // S^T = K_tile · Q^T (3-pass hi/lo). K A-frags from LDS: lane (h,l31)
    // reads (ks*4+2h+m)*256 + l31*8 us — 16B/lane contiguous per half-wave.
    f32x16 s[2] = {};
    __builtin_amdgcn_s_setprio(1);
    #pragma unroll
    for (int ks = 0; ks < 4; ++ks) {
      #pragma unroll
      for (int m = 0; m < 2; ++m) {
        const int ko = (ks * 4 + 2 * h + m) * 256 + l31 * 8;
        const bf16x8 ah = *(const bf16x8*)(sb + ko);
        const bf16x8 al = *(const bf16x8*)(sb + 4096 + ko);
        s[m] = mfma(ah, qh[ks], s[m]);
        s[m] = mfma(al, qh[ks], s[m]);
        s[m] = mfma(ah, ql[ks], s[m]);
      }
    }
    __builtin_amdgcn_s_setprio(0);

    // tile max: two fmax chains (max3-fusable), then cross-half swap
    float va = fmaxf(s[0][0], s[1][0]);
    float vb = fmaxf(s[0][1], s[1][1]);
    #pragma unroll
    for (int r = 2; r < 16; r += 2) {
      va = fmaxf(va, fmaxf(s[0][r], s[1][r]));
      vb = fmaxf(vb, fmaxf(s[0][r + 1], s[1][r + 1]));
    }
    float vm = fmaxf(va, vb);
    vm = fmaxf(vm, __shfl_xor(vm, 32));

    // near-one-hot skip: tile contributes < 2^-24 of lrun -> drop it
    // (wave-uniform branch; barriers stay OUTSIDE it)
    if (!__all(vm <= mrun - 24.f)) {
      // rescale tolerance: only adopt a higher max if it rose by > 0.5
      const float mnew = (vm > mrun + 0.5f) ? vm : mrun;
      const float alpha = EXP2(mrun - mnew);    // 1.0 when mnew==mrun
      float sm0 = 0.f, sm1 = 0.f;               // two chains, shorter deps
      unsigned pp[2][8];
      #pragma unroll
      for (int m = 0; m < 2; ++m) {
        #pragma unroll
        for (int p = 0; p < 8; ++p) {
          const float p0 = EXP2(s[m][2 * p] - mnew);
          const float p1 = EXP2(s[m][2 * p + 1] - mnew);
          sm0 += p0;
          sm1 += p1;
          pp[m][p] = pk2t(p0, p1);              // one v_perm per pair
        }
      }
      float sum = sm0 + sm1;
      sum += __shfl_xor(sum, 32);
      lrun = lrun * alpha + sum;
      mrun = mnew;

      // rescale O (rare; alds broadcast to C-layout rows; per-wave LDS)
      if (__any(alpha != 1.f)) {
        if (!h) alds[wid][l31] = alpha;
        #pragma unroll
        for (int g = 0; g < 4; ++g) {
          const float4 af4 = *(const float4*)(&alds[wid][8 * g + 4 * h]);
          #pragma unroll
          for (int rr = 0; rr < 4; ++rr) {
            const int r = 4 * g + rr;
            const float a = (rr == 0) ? af4.x : (rr == 1) ? af4.y
                           : (rr == 2) ? af4.z : af4.w;
            o[0][r] *= a;
            o[1][r] *= a;
          }
        }
      }

      // PV: P A-frags via permlane32_swap pairs; V B-frags from LDS.
      __builtin_amdgcn_s_setprio(1);
      #pragma unroll
      for (int ks = 0; ks < 4; ++ks) {
        const int vo = 8192 + (ks * 4 + 2 * h) * 256 + l31 * 8;
        const bf16x8 vf0 = *(const bf16x8*)(sb + vo);
        const bf16x8 vf1 = *(const bf16x8*)(sb + vo + 256);
        const int m = ks >> 1, base = 4 * (ks & 1);
        unsigned wx = pp[m][base + 0], wz = pp[m][base + 2];
        unsigned wy = pp[m][base + 1], ww = pp[m][base + 3];
        asm("v_permlane32_swap_b32 %0, %1" : "+v"(wx), "+v"(wz));
        asm("v_permlane32_swap_b32 %0, %1" : "+v"(wy), "+v"(ww));
        u32x4 wv;
        wv.x = wx;
        wv.y = wy;
        wv.z = wz;
        wv.w = ww;
        const bf16x8 af = __builtin_bit_cast(bf16x8, wv);
        o[0] = mfma(af, vf0, o[0]);
        o[1] = mfma(af, vf1, o[1]);
      }
      __builtin_amdgcn_s_setprio(0);
    }

    // drain next-tile DMA (landed during compute) + protect buffer swap
    __syncthreads();
  }

  // epilogue: O -> bf16 Opart via LDS bounce aliasing the dead stage
  // buffers (per-wave 32x34 f32 region), two dt passes. No barriers.
  float* fw = ((float*)&stage[0][0]) + wid * (32 * 34);
  #pragma unroll
  for (int dt = 0; dt < 2; ++dt) {
    #pragma unroll
    for (int r = 0; r < 16; ++r) {
      const int qrow = (r & 3) + 8 * (r >> 2) + 4 * h;  // 0..31
      fw[qrow * 34 + l31] = o[dt][r];
    }
    #pragma unroll
    for (int jj = 0; jj < 2; ++jj) {
      const int chunk = lane + 64 * jj;           // 0..127
      const int rw = chunk >> 2, part = chunk & 3;
      const float* src = &fw[rw * 34 + part * 8];
      float2 a0 = *(const float2*)(src + 0);
      float2 a1 = *(const float2*)(src + 2);
      float2 a2 = *(const float2*)(src + 4);
      float2 a3 = *(const float2*)(src + 6);
      uint4 pkv;
      pkv.x = pk2t(a0.x, a0.y);
      pkv.y = pk2t(a1.x, a1.y);
      pkv.z = pk2t(a2.x, a2.y);
      pkv.w = pk2t(a3.x, a3.y);
      *(uint4*)(Opart + pb * 2048 + (size_t)rw * 64 + dt * 32 + part * 8) =
          pkv;
    }
  }
  if (!h) {
    Mpart[pb * 32 + l31] = mrun;
    Lpart[pb * 32 + l31] = lrun;
  }
}

// ---------------------------------------------------------------------------
// Kernel 3: merge 4 key-segment partials (bf16). 131072 thr, 8 d each.
// ---------------------------------------------------------------------------
__global__ __launch_bounds__(256, 1) void merge_kernel(
    const us* __restrict__ Opart, const float* __restrict__ Mpart,
    const float* __restrict__ Lpart, float* __restrict__ out)
{
  const int tg = blockIdx.x * 256 + threadIdx.x;
  const int q = tg >> 3, dc = (tg & 7) * 8;
  const int u = q >> 5, ql = q & 31;
  const int base = u * NSEG;
  float M = -__builtin_inff();
  #pragma unroll
  for (int s = 0; s < NSEG; ++s)
    M = fmaxf(M, Mpart[(size_t)(base + s) * 32 + ql]);
  float acc[8] = {};
  float den = 0.f;
  #pragma unroll
  for (int s = 0; s < NSEG; ++s) {
    const float wgt = EXP2(Mpart[(size_t)(base + s) * 32 + ql] - M);
    den += wgt * Lpart[(size_t)(base + s) * 32 + ql];
    const uint4 r = *(const uint4*)(Opart + (size_t)(base + s) * 2048 +
                                    ql * 64 + dc);
    const unsigned rw[4] = {r.x, r.y, r.z, r.w};
    #pragma unroll
    for (int j = 0; j < 4; ++j) {
      acc[2 * j]     += wgt * bf2f((us)(rw[j] & 0xffffu));
      acc[2 * j + 1] += wgt * bf2f((us)(rw[j] >> 16));
    }
  }
  const float inv = 1.f / den;
  float4 r0 = {acc[0] * inv, acc[1] * inv, acc[2] * inv, acc[3] * inv};
  float4 r1 = {acc[4] * inv, acc[5] * inv, acc[6] * inv, acc[7] * inv};
  *(float4*)(out + (size_t)q * 64 + dc) = r0;
  *(float4*)(out + (size_t)q * 64 + dc + 4) = r1;
}

// ---------------------------------------------------------------------------
extern "C" void kernel_launch(void* const* d_in, const int* in_sizes, int n_in,
                              void* d_out, int out_size, void* d_ws,
                              size_t ws_size, hipStream_t stream)
{
  const float* x = (const float*)d_in[0];
  const float* w = (const float*)d_in[1];
  float* out = (float*)d_out;
  char* ws = (char*)d_ws;

  const size_t T = 2097152;  // bytes per bf16 [4,4096,64] tensor
  us* Qhi = (us*)(ws + 0 * T);
  us* Qlo = (us*)(ws + 1 * T);
  us* Kbh = (us*)(ws + 2 * T);
  us* Kbl = (us*)(ws + 3 * T);
  us* Vb  = (us*)(ws + 4 * T);
  char* pbase = ws + 5 * T;
  us* Opart = (us*)pbase;                                    // 8,388,608 B
  float* Mpart = (float*)(pbase + 8388608);                  //   262,144 B
  float* Lpart = (float*)(pbase + 8388608 + 262144);         //   262,144 B
  // total workspace use: ~18.5 MiB

  hipLaunchKernelGGL(qkv_kernel, dim3(512), dim3(384), 0, stream,
                     x, w, Qhi, Qlo, Kbh, Kbl, Vb);
  hipLaunchKernelGGL(attn_kernel, dim3(512), dim3(256), 0, stream,
                     Qhi, Qlo, Kbh, Kbl, Vb, Opart, Mpart, Lpart);
  hipLaunchKernelGGL(merge_kernel, dim3(512), dim3(256), 0, stream,
                     Opart, Mpart, Lpart, out);
}